// Round 19
// baseline (198.021 us; speedup 1.0000x reference)
//
#include <hip/hip_runtime.h>
#include <math.h>

#define NB 46
#define NS 50
#define ND 768
#define GAMA 0.96875f
#define NM 2300   // NB*NS rows

using bfrag  = __attribute__((ext_vector_type(8))) short;   // 8 bf16 = 4 VGPRs
using f32x16 = __attribute__((ext_vector_type(16))) float;  // 32x32 acc
using f32x4  = __attribute__((ext_vector_type(4)))  float;  // 16x16 acc

union FragU { unsigned u[4]; bfrag f; };

// hi/lo bf16 split of 8 f32 (truncation; combined ~16-bit mantissa)
__device__ __forceinline__ void cvt_hilo(const float f[8], bfrag& fh, bfrag& fl)
{
    FragU uh, ul;
    #pragma unroll
    for (int t = 0; t < 4; t++) {
        const unsigned b0 = __float_as_uint(f[2 * t]);
        const unsigned b1 = __float_as_uint(f[2 * t + 1]);
        uh.u[t] = (b0 >> 16) | (b1 & 0xFFFF0000u);
        const float r0 = f[2 * t]     - __uint_as_float(b0 & 0xFFFF0000u);
        const float r1 = f[2 * t + 1] - __uint_as_float(b1 & 0xFFFF0000u);
        ul.u[t] = (__float_as_uint(r0) >> 16) | (__float_as_uint(r1) & 0xFFFF0000u);
    }
    fh = uh.f; fl = ul.f;
}

// ---------------- Kernel 1: QKV projections via MFMA + LDS staging --------
// R16 version EXACTLY (R18's dbuf cost occupancy, +7.6us — reverted).
__global__ __launch_bounds__(256) void qkv_gemm(
    const float* __restrict__ text_emb, const float* __restrict__ emb,
    const float* __restrict__ Wq, const float* __restrict__ bq,
    const float* __restrict__ Wk, const float* __restrict__ bk,
    const float* __restrict__ Wv, const float* __restrict__ bv,
    float* __restrict__ Q, float* __restrict__ K, float* __restrict__ V)
{
    const int z = blockIdx.z;
    const float* X    = (z == 0) ? text_emb : emb;
    const float* W    = (z == 0) ? Wq : (z == 1) ? Wk : Wv;
    const float* bias = (z == 0) ? bq : (z == 1) ? bk : bv;
    float* out        = (z == 0) ? Q  : (z == 1) ? K  : V;

    __shared__ float Xs[32][68];
    __shared__ float Ws[32][68];

    const int tid = threadIdx.x;
    const int w   = tid >> 6;           // wave 0..3
    const int l   = tid & 63;
    const int c   = l & 31;
    const int h   = l >> 5;
    const int wm  = w >> 1, wn = w & 1; // quadrant
    const int m0  = blockIdx.x * 64, n0 = blockIdx.y * 64;

    const int lrow = tid >> 2;          // 0..63
    const int lk   = (tid & 3) * 4;     // 0,4,8,12
    const int xm   = m0 + lrow;
    const float* __restrict__ Xrow = X + (size_t)(xm < NM ? xm : 0) * ND;
    const float* __restrict__ Wrow = W + (size_t)(n0 + lrow) * ND;

    f32x16 acc;
    #pragma unroll
    for (int g = 0; g < 16; g++) acc[g] = 0.f;

    for (int k0 = 0; k0 < ND; k0 += 32) {
        const float4 xv0 = *reinterpret_cast<const float4*>(&Xrow[k0 + lk]);
        const float4 xv1 = *reinterpret_cast<const float4*>(&Xrow[k0 + 16 + lk]);
        const float4 wv0 = *reinterpret_cast<const float4*>(&Wrow[k0 + lk]);
        const float4 wv1 = *reinterpret_cast<const float4*>(&Wrow[k0 + 16 + lk]);
        __syncthreads();
        Xs[lk + 0][lrow] = xv0.x; Xs[lk + 1][lrow] = xv0.y;
        Xs[lk + 2][lrow] = xv0.z; Xs[lk + 3][lrow] = xv0.w;
        Xs[16 + lk + 0][lrow] = xv1.x; Xs[16 + lk + 1][lrow] = xv1.y;
        Xs[16 + lk + 2][lrow] = xv1.z; Xs[16 + lk + 3][lrow] = xv1.w;
        Ws[lk + 0][lrow] = wv0.x; Ws[lk + 1][lrow] = wv0.y;
        Ws[lk + 2][lrow] = wv0.z; Ws[lk + 3][lrow] = wv0.w;
        Ws[16 + lk + 0][lrow] = wv1.x; Ws[16 + lk + 1][lrow] = wv1.y;
        Ws[16 + lk + 2][lrow] = wv1.z; Ws[16 + lk + 3][lrow] = wv1.w;
        __syncthreads();

        #pragma unroll
        for (int kt = 0; kt < 2; kt++) {
            float fx[8], fw[8];
            #pragma unroll
            for (int j = 0; j < 8; j++) {
                fx[j] = Xs[16 * kt + 8 * h + j][32 * wm + c];
                fw[j] = Ws[16 * kt + 8 * h + j][32 * wn + c];
            }
            bfrag Ah, Al, Bh, Bl;
            cvt_hilo(fx, Ah, Al);
            cvt_hilo(fw, Bh, Bl);
            acc = __builtin_amdgcn_mfma_f32_32x32x16_bf16(Ah, Bh, acc, 0, 0, 0);
            acc = __builtin_amdgcn_mfma_f32_32x32x16_bf16(Ah, Bl, acc, 0, 0, 0);
            acc = __builtin_amdgcn_mfma_f32_32x32x16_bf16(Al, Bh, acc, 0, 0, 0);
        }
    }

    const float C2 = -0.0239861701969175f; // -2*ln(10000)/768
    const int n = n0 + 32 * wn + c;
    #pragma unroll
    for (int g = 0; g < 16; g++) {
        const int rr = (g & 3) + 8 * (g >> 2) + 4 * h;
        const int m  = m0 + 32 * wm + rr;
        if (m >= NM) continue;
        float v = acc[g] + bias[n];
        if (z < 2) {
            const int bpos = m / NS;  // pe indexed by BATCH position (faithful)
            const float ang = (float)bpos * expf((float)(n >> 1) * C2);
            v += (n & 1) ? cosf(ang) : sinf(ang);
        }
        out[(size_t)m * ND + n] = v;
    }
}

// ---------------- Kernel 2: attention via MFMA, one block per b ------------
// (R15 version, unchanged.)
__global__ __launch_bounds__(256, 1) void attn(
    const float* __restrict__ Q, const float* __restrict__ K,
    const float* __restrict__ V,
    const float* __restrict__ lin_w, const float* __restrict__ lin_b,
    float* __restrict__ Ag, float* __restrict__ ctx_out)
{
    const int b   = blockIdx.x;
    const int tid = threadIdx.x;
    const int w   = tid >> 6;          // wave 0..3
    const int l   = tid & 63;
    const int c   = l & 31;
    const int h   = l >> 5;

    __shared__ float Lsh[9 * 64 * 68];           // 153 KB
    float* SP = Lsh;                              // 4 partial S tiles
    float* QP = Lsh + 4 * 64 * 68;                // 4 partial Qt tiles
    float* Pf = Lsh + 8 * 64 * 68;                // P

    const float* __restrict__ Qb = Q + (size_t)b * NS * ND;
    const float* __restrict__ Kb = K + (size_t)b * NS * ND;
    const float* __restrict__ Vb = V + (size_t)b * NS * ND;

    f32x16 accS[2][2], accQ[2][2];
    #pragma unroll
    for (int mt = 0; mt < 2; mt++)
        #pragma unroll
        for (int nt = 0; nt < 2; nt++)
            #pragma unroll
            for (int g = 0; g < 16; g++) { accS[mt][nt][g] = 0.f; accQ[mt][nt][g] = 0.f; }

    const int ks = w * 192;
    for (int kt = 0; kt < 12; ++kt) {
        const int ko = ks + kt * 16 + 8 * h;
        bfrag Qh[2], Ql[2], Kh[2], Kl[2], Wh[2], Wl[2];
        #pragma unroll
        for (int mt = 0; mt < 2; mt++) {
            const int row = 32 * mt + c;
            const int r = (row < NS) ? row : 0;
            float f[8];
            {
                const float4 a0 = *reinterpret_cast<const float4*>(&Qb[(size_t)r * ND + ko]);
                const float4 a1 = *reinterpret_cast<const float4*>(&Qb[(size_t)r * ND + ko + 4]);
                f[0]=a0.x; f[1]=a0.y; f[2]=a0.z; f[3]=a0.w; f[4]=a1.x; f[5]=a1.y; f[6]=a1.z; f[7]=a1.w;
            }
            cvt_hilo(f, Qh[mt], Ql[mt]);
            {
                const float4 a0 = *reinterpret_cast<const float4*>(&Kb[(size_t)r * ND + ko]);
                const float4 a1 = *reinterpret_cast<const float4*>(&Kb[(size_t)r * ND + ko + 4]);
                f[0]=a0.x; f[1]=a0.y; f[2]=a0.z; f[3]=a0.w; f[4]=a1.x; f[5]=a1.y; f[6]=a1.z; f[7]=a1.w;
            }
            cvt_hilo(f, Kh[mt], Kl[mt]);
            {
                const float4 a0 = *reinterpret_cast<const float4*>(&lin_w[(size_t)r * ND + ko]);
                const float4 a1 = *reinterpret_cast<const float4*>(&lin_w[(size_t)r * ND + ko + 4]);
                f[0]=a0.x; f[1]=a0.y; f[2]=a0.z; f[3]=a0.w; f[4]=a1.x; f[5]=a1.y; f[6]=a1.z; f[7]=a1.w;
            }
            cvt_hilo(f, Wh[mt], Wl[mt]);
        }
        #pragma unroll
        for (int mt = 0; mt < 2; mt++)
            #pragma unroll
            for (int nt = 0; nt < 2; nt++) {
                f32x16 a = accS[mt][nt];
                a = __builtin_amdgcn_mfma_f32_32x32x16_bf16(Qh[mt], Kh[nt], a, 0, 0, 0);
                a = __builtin_amdgcn_mfma_f32_32x32x16_bf16(Qh[mt], Kl[nt], a, 0, 0, 0);
                a = __builtin_amdgcn_mfma_f32_32x32x16_bf16(Ql[mt], Kh[nt], a, 0, 0, 0);
                accS[mt][nt] = a;
                f32x16 q = accQ[mt][nt];
                q = __builtin_amdgcn_mfma_f32_32x32x16_bf16(Qh[mt], Wh[nt], q, 0, 0, 0);
                q = __builtin_amdgcn_mfma_f32_32x32x16_bf16(Qh[mt], Wl[nt], q, 0, 0, 0);
                q = __builtin_amdgcn_mfma_f32_32x32x16_bf16(Ql[mt], Wh[nt], q, 0, 0, 0);
                accQ[mt][nt] = q;
            }
    }

    {
        float* SPw = SP + w * (64 * 68);
        float* QPw = QP + w * (64 * 68);
        #pragma unroll
        for (int mt = 0; mt < 2; mt++)
            #pragma unroll
            for (int nt = 0; nt < 2; nt++)
                #pragma unroll
                for (int g = 0; g < 16; g++) {
                    const int rg  = 32 * mt + (g & 3) + 8 * (g >> 2) + 4 * h;
                    const int col = 32 * nt + c;
                    SPw[rg * 68 + col] = accS[mt][nt][g];
                    QPw[rg * 68 + col] = accQ[mt][nt][g];
                }
    }
    __syncthreads();

    {
        const int r  = tid >> 2;
        const int cg = (tid & 3) * 16;
        #pragma unroll
        for (int q4 = 0; q4 < 4; ++q4) {
            const int off = r * 68 + cg + q4 * 4;
            float4 s0 = *reinterpret_cast<const float4*>(&SP[off]);
            float4 s1 = *reinterpret_cast<const float4*>(&SP[64 * 68 + off]);
            float4 s2 = *reinterpret_cast<const float4*>(&SP[2 * 64 * 68 + off]);
            float4 s3 = *reinterpret_cast<const float4*>(&SP[3 * 64 * 68 + off]);
            float4 r4;
            r4.x = 8.f * ((s0.x + s1.x) + (s2.x + s3.x));
            r4.y = 8.f * ((s0.y + s1.y) + (s2.y + s3.y));
            r4.z = 8.f * ((s0.z + s1.z) + (s2.z + s3.z));
            r4.w = 8.f * ((s0.w + s1.w) + (s2.w + s3.w));
            *reinterpret_cast<float4*>(&SP[off]) = r4;
            float4 t0 = *reinterpret_cast<const float4*>(&QP[off]);
            float4 t1 = *reinterpret_cast<const float4*>(&QP[64 * 68 + off]);
            float4 t2 = *reinterpret_cast<const float4*>(&QP[2 * 64 * 68 + off]);
            float4 t3 = *reinterpret_cast<const float4*>(&QP[3 * 64 * 68 + off]);
            float4 u4;
            u4.x = (t0.x + t1.x) + (t2.x + t3.x);
            u4.y = (t0.y + t1.y) + (t2.y + t3.y);
            u4.z = (t0.z + t1.z) + (t2.z + t3.z);
            u4.w = (t0.w + t1.w) + (t2.w + t3.w);
            *reinterpret_cast<float4*>(&QP[off]) = u4;
        }
    }
    __syncthreads();

    if (tid < NS) {
        const float* Sr = SP + tid * 68;
        float mx = -INFINITY;
        for (int c2 = 0; c2 < NS; ++c2) mx = fmaxf(mx, Sr[c2]);
        float sum = 0.f;
        for (int c2 = 0; c2 < NS; ++c2) {
            const float e = expf(Sr[c2] - mx);
            Pf[tid * 68 + c2] = e;
            sum += e;
        }
        const float inv = 1.f / sum;
        for (int c2 = 0; c2 < NS; ++c2) Pf[tid * 68 + c2] *= inv;
        for (int c2 = NS; c2 < 64; ++c2) Pf[tid * 68 + c2] = 0.f;
    }
    for (int e = tid; e < NS * NS; e += 256) {
        const int r = e / NS, cc = e - r * NS;
        Ag[b * (NS * NS) + e] = GAMA * (QP[r * 68 + cc] + lin_b[cc]);
    }
    __syncthreads();

    bfrag Ph[2][4], Pl[2][4];
    #pragma unroll
    for (int mt = 0; mt < 2; mt++)
        #pragma unroll
        for (int kt = 0; kt < 4; kt++) {
            float f[8];
            #pragma unroll
            for (int j = 0; j < 8; j++)
                f[j] = Pf[(32 * mt + c) * 68 + kt * 16 + 8 * h + j];
            cvt_hilo(f, Ph[mt][kt], Pl[mt][kt]);
        }

    for (int j3 = 0; j3 < 3; ++j3) {
        const int dbase = (w * 3 + j3) * 64;
        f32x16 accC[2][2];
        #pragma unroll
        for (int mt = 0; mt < 2; mt++)
            #pragma unroll
            for (int nt = 0; nt < 2; nt++)
                #pragma unroll
                for (int g = 0; g < 16; g++) accC[mt][nt][g] = 0.f;

        #pragma unroll
        for (int nt = 0; nt < 2; nt++) {
            const int d = dbase + 32 * nt + c;
            #pragma unroll
            for (int kt = 0; kt < 4; kt++) {
                float f[8];
                #pragma unroll
                for (int j = 0; j < 8; j++) {
                    const int k2 = kt * 16 + 8 * h + j;
                    f[j] = (k2 < NS) ? Vb[(size_t)k2 * ND + d] : 0.f;
                }
                bfrag Bh, Bl;
                cvt_hilo(f, Bh, Bl);
                #pragma unroll
                for (int mt = 0; mt < 2; mt++) {
                    f32x16 a = accC[mt][nt];
                    a = __builtin_amdgcn_mfma_f32_32x32x16_bf16(Ph[mt][kt], Bh, a, 0, 0, 0);
                    a = __builtin_amdgcn_mfma_f32_32x32x16_bf16(Ph[mt][kt], Bl, a, 0, 0, 0);
                    a = __builtin_amdgcn_mfma_f32_32x32x16_bf16(Pl[mt][kt], Bh, a, 0, 0, 0);
                    accC[mt][nt] = a;
                }
            }
        }
        #pragma unroll
        for (int mt = 0; mt < 2; mt++)
            #pragma unroll
            for (int nt = 0; nt < 2; nt++)
                #pragma unroll
                for (int g = 0; g < 16; g++) {
                    const int rg = 32 * mt + (g & 3) + 8 * (g >> 2) + 4 * h;
                    if (rg < NS)
                        ctx_out[((size_t)b * NS + rg) * ND + dbase + 32 * nt + c] = accC[mt][nt][g];
                }
    }
}

// ---------------- Kernel 3: gamma-decay recurrence, 16x16x32 MFMA ----------
// R18 analysis: R13's recur (105us) is latency-exposed at 1.08 waves/SIMD and
// that cap is the GRID (1104 one-wave tasks / 1024 SIMDs), not VGPR/LDS.
// R17 (barrier-coupled wave split) failed; wave-packing can't change total
// wave count. Only true TLP lever: more, smaller independent tasks ->
// 16-col chunks via mfma_f32_16x16x32_bf16 (half the FLOP per MFMA, so
// per-block work halves at the same 24 MFMA/step): grid 2208 = 2.16
// waves/SIMD, still barrier-free single-wave blocks. Layouts (16x16x32):
// A row=16mt+(l&15), k=32kt+8*(l>>4)+j; B col=l&15, same k; C/D col=l&15,
// row=16mt+4*(l>>4)+g. Fat VMEM: 4 loads + 4 stores/step (16 rows x 64B per
// op). Same hi/lo split, same load-before-store FIFO discipline as R13.
__global__ __launch_bounds__(64, 1) void recur(
    const float* __restrict__ Ag, const float* __restrict__ ctx,
    float* __restrict__ rec)
{
    const int blk   = blockIdx.x;          // 0..2207
    const int b     = blk / 48;
    const int chunk = blk - b * 48;        // 0..47 -> 16 cols
    const int l     = threadIdx.x;
    const int c16   = l & 15;
    const int q4    = l >> 4;              // 0..3
    const int d0    = chunk * 16;
    const int srow  = l >> 2;              // 0..15 (fat-op tile row)
    const int scol  = (l & 3) * 4;         // 0,4,8,12 (fat-op tile col)

    __shared__ float Sf[64 * 16];          // state f32, 4 KB
    __shared__ float Cx[64 * 16];          // ctx staging, 4 KB

    // ---- A fragments (hi/lo), ONCE from global: mt 0..3, kt 0..1 ----
    const float* __restrict__ Ab = Ag + b * (NS * NS);
    bfrag Ah[4][2], Al[4][2];
    #pragma unroll
    for (int mt = 0; mt < 4; mt++) {
        const int row = 16 * mt + c16;
        const bool rok = row < NS;
        const float* __restrict__ Arow = Ab + row * NS;
        #pragma unroll
        for (int kt = 0; kt < 2; kt++) {
            FragU uh, ul;
            #pragma unroll
            for (int t = 0; t < 4; t++) {
                const int k0 = 32 * kt + 8 * q4 + 2 * t;
                const float e = (rok && k0     < NS) ? Arow[k0]     : 0.f;
                const float o = (rok && k0 + 1 < NS) ? Arow[k0 + 1] : 0.f;
                const unsigned ue = __float_as_uint(e), uo = __float_as_uint(o);
                uh.u[t] = (ue >> 16) | (uo & 0xFFFF0000u);
                const float re = e - __uint_as_float(ue & 0xFFFF0000u);
                const float ro = o - __uint_as_float(uo & 0xFFFF0000u);
                ul.u[t] = (__float_as_uint(re) >> 16) | (__float_as_uint(ro) & 0xFFFF0000u);
            }
            Ah[mt][kt] = uh.f; Al[mt][kt] = ul.f;
        }
    }

    // ---- zero pad rows 48..63 (rows 48,49 overwritten each step) ----
    {
        const float4 z = make_float4(0.f, 0.f, 0.f, 0.f);
        *reinterpret_cast<float4*>(&Cx[(48 + srow) * 16 + scol]) = z;
        *reinterpret_cast<float4*>(&Sf[(48 + srow) * 16 + scol]) = z;
    }

    // ---- step 0: fat load ctx0 -> Sf + rec0; prefetch ctx1 (FIFO order) ----
    float4 creg[4];
    #pragma unroll
    for (int it = 0; it < 4; ++it) creg[it] = make_float4(0.f, 0.f, 0.f, 0.f);
    {
        const float* __restrict__ src = ctx + d0;
        float4 c0[4];
        #pragma unroll
        for (int it = 0; it < 4; ++it) {
            c0[it] = make_float4(0.f, 0.f, 0.f, 0.f);
            const int r = it * 16 + srow;
            if (r < NS)
                c0[it] = *reinterpret_cast<const float4*>(&src[(size_t)r * ND + scol]);
        }
        const float* __restrict__ s1 = ctx + (size_t)NS * ND + d0;
        #pragma unroll
        for (int it = 0; it < 4; ++it) {
            const int r = it * 16 + srow;
            if (r < NS)
                creg[it] = *reinterpret_cast<const float4*>(&s1[(size_t)r * ND + scol]);
        }
        float* __restrict__ r0 = rec + (size_t)b * NS * ND + d0;
        #pragma unroll
        for (int it = 0; it < 4; ++it) {
            const int r = it * 16 + srow;
            if (r < NS) {
                *reinterpret_cast<float4*>(&Sf[r * 16 + scol]) = c0[it];
                *reinterpret_cast<float4*>(&r0[(size_t)r * ND + scol]) = c0[it];
            }
        }
    }

    // ---- steps 1..45 (single-wave program order; no barriers) ----
    for (int i = 1; i < NB; ++i) {
        // [A] flush creg (ctx_i) -> Cx
        #pragma unroll
        for (int it = 0; it < 4; ++it) {
            const int r = it * 16 + srow;
            if (r < NS)
                *reinterpret_cast<float4*>(&Cx[r * 16 + scol]) = creg[it];
        }
        // [B] fat loads of ctx_{i+1} (BEFORE this step's stores)
        if (i + 1 < NB) {
            const float* __restrict__ src = ctx + (size_t)(i + 1) * NS * ND + d0;
            #pragma unroll
            for (int it = 0; it < 4; ++it) {
                const int r = it * 16 + srow;
                if (r < NS)
                    creg[it] = *reinterpret_cast<const float4*>(&src[(size_t)r * ND + scol]);
            }
        }
        // [C] acc init from Cx (pad rows exact 0)
        f32x4 acc[4];
        #pragma unroll
        for (int mt = 0; mt < 4; mt++)
            #pragma unroll
            for (int g = 0; g < 4; g++) {
                const int rg = 16 * mt + 4 * q4 + g;
                acc[mt][g] = Cx[rg * 16 + c16];
            }
        // [D] B-frags of s_{i-1} from Sf (pack hi/lo)
        bfrag Bh[2], Bl[2];
        #pragma unroll
        for (int kt = 0; kt < 2; kt++) {
            float f[8];
            #pragma unroll
            for (int j = 0; j < 8; j++)
                f[j] = Sf[(32 * kt + 8 * q4 + j) * 16 + c16];
            cvt_hilo(f, Bh[kt], Bl[kt]);
        }
        // [E] per mt: hh x2kt, hl x2kt, lh x2kt
        #pragma unroll
        for (int mt = 0; mt < 4; mt++) {
            f32x4 a = acc[mt];
            #pragma unroll
            for (int kt = 0; kt < 2; kt++)
                a = __builtin_amdgcn_mfma_f32_16x16x32_bf16(Ah[mt][kt], Bh[kt], a, 0, 0, 0);
            #pragma unroll
            for (int kt = 0; kt < 2; kt++)
                a = __builtin_amdgcn_mfma_f32_16x16x32_bf16(Ah[mt][kt], Bl[kt], a, 0, 0, 0);
            #pragma unroll
            for (int kt = 0; kt < 2; kt++)
                a = __builtin_amdgcn_mfma_f32_16x16x32_bf16(Al[mt][kt], Bh[kt], a, 0, 0, 0);
            acc[mt] = a;
        }
        // [F] acc -> Sf (all 64 rows; pad rows produce exact 0)
        #pragma unroll
        for (int mt = 0; mt < 4; mt++)
            #pragma unroll
            for (int g = 0; g < 4; g++) {
                const int rg = 16 * mt + 4 * q4 + g;
                Sf[rg * 16 + c16] = acc[mt][g];
            }
        // [G]+[H] fat read-back + fat stores of rec_i
        float* __restrict__ reci = rec + (size_t)(i * NB + b) * NS * ND + d0;
        #pragma unroll
        for (int it = 0; it < 4; ++it) {
            const int r = it * 16 + srow;
            if (r < NS) {
                const float4 v = *reinterpret_cast<const float4*>(&Sf[r * 16 + scol]);
                *reinterpret_cast<float4*>(&reci[(size_t)r * ND + scol]) = v;
            }
        }
    }
}

extern "C" void kernel_launch(void* const* d_in, const int* in_sizes, int n_in,
                              void* d_out, int out_size, void* d_ws, size_t ws_size,
                              hipStream_t stream) {
    const float* text_emb = (const float*)d_in[0];
    const float* emb      = (const float*)d_in[1];
    const float* Wq = (const float*)d_in[2]; const float* bq = (const float*)d_in[3];
    const float* Wk = (const float*)d_in[4]; const float* bk = (const float*)d_in[5];
    const float* Wv = (const float*)d_in[6]; const float* bv = (const float*)d_in[7];
    const float* lw = (const float*)d_in[8]; const float* lb = (const float*)d_in[9];

    float* out = (float*)d_out;
    float* ctx = out;                          // [46,50,768]
    float* rec = out + NB * NS * ND;           // [46,46,50,768]

    float* ws = (float*)d_ws;                  // needs 21.7 MB
    float* Q  = ws;
    float* K  = Q + NB * NS * ND;
    float* V  = K + NB * NS * ND;
    float* Ag = V + NB * NS * ND;              // gamma * Q_trans, [46,50,50]

    qkv_gemm<<<dim3(36, 12, 3), 256, 0, stream>>>(text_emb, emb, Wq, bq, Wk, bk, Wv, bv, Q, K, V);
    attn<<<dim3(NB), 256, 0, stream>>>(Q, K, V, lw, lb, Ag, ctx);
    recur<<<dim3(2208), 64, 0, stream>>>(Ag, ctx, rec);
}

// Round 20
// 189.570 us; speedup vs baseline: 1.0446x; 1.0446x over previous
//
#include <hip/hip_runtime.h>
#include <math.h>

#define NB 46
#define NS 50
#define ND 768
#define GAMA 0.96875f
#define NM 2300   // NB*NS rows

using bfrag  = __attribute__((ext_vector_type(8))) short;   // 8 bf16 = 4 VGPRs
using f32x16 = __attribute__((ext_vector_type(16))) float;  // 32x32 acc

union FragU { unsigned u[4]; bfrag f; };

// hi/lo bf16 split of 8 f32 (truncation; combined ~16-bit mantissa)
__device__ __forceinline__ void cvt_hilo(const float f[8], bfrag& fh, bfrag& fl)
{
    FragU uh, ul;
    #pragma unroll
    for (int t = 0; t < 4; t++) {
        const unsigned b0 = __float_as_uint(f[2 * t]);
        const unsigned b1 = __float_as_uint(f[2 * t + 1]);
        uh.u[t] = (b0 >> 16) | (b1 & 0xFFFF0000u);
        const float r0 = f[2 * t]     - __uint_as_float(b0 & 0xFFFF0000u);
        const float r1 = f[2 * t + 1] - __uint_as_float(b1 & 0xFFFF0000u);
        ul.u[t] = (__float_as_uint(r0) >> 16) | (__float_as_uint(r1) & 0xFFFF0000u);
    }
    fh = uh.f; fl = ul.f;
}

// ---------------- Kernel 1: QKV projections via MFMA + LDS staging --------
// R16 version EXACTLY (best measured; R18 dbuf and R14 row-strided variants
// both regressed). Coalesced float4 staging -> k-major LDS [32][68] ->
// conflict-free frag reads -> hi/lo bf16 MFMA.
__global__ __launch_bounds__(256) void qkv_gemm(
    const float* __restrict__ text_emb, const float* __restrict__ emb,
    const float* __restrict__ Wq, const float* __restrict__ bq,
    const float* __restrict__ Wk, const float* __restrict__ bk,
    const float* __restrict__ Wv, const float* __restrict__ bv,
    float* __restrict__ Q, float* __restrict__ K, float* __restrict__ V)
{
    const int z = blockIdx.z;
    const float* X    = (z == 0) ? text_emb : emb;
    const float* W    = (z == 0) ? Wq : (z == 1) ? Wk : Wv;
    const float* bias = (z == 0) ? bq : (z == 1) ? bk : bv;
    float* out        = (z == 0) ? Q  : (z == 1) ? K  : V;

    __shared__ float Xs[32][68];
    __shared__ float Ws[32][68];

    const int tid = threadIdx.x;
    const int w   = tid >> 6;           // wave 0..3
    const int l   = tid & 63;
    const int c   = l & 31;
    const int h   = l >> 5;
    const int wm  = w >> 1, wn = w & 1; // quadrant
    const int m0  = blockIdx.x * 64, n0 = blockIdx.y * 64;

    const int lrow = tid >> 2;          // 0..63
    const int lk   = (tid & 3) * 4;     // 0,4,8,12
    const int xm   = m0 + lrow;
    const float* __restrict__ Xrow = X + (size_t)(xm < NM ? xm : 0) * ND;
    const float* __restrict__ Wrow = W + (size_t)(n0 + lrow) * ND;

    f32x16 acc;
    #pragma unroll
    for (int g = 0; g < 16; g++) acc[g] = 0.f;

    for (int k0 = 0; k0 < ND; k0 += 32) {
        const float4 xv0 = *reinterpret_cast<const float4*>(&Xrow[k0 + lk]);
        const float4 xv1 = *reinterpret_cast<const float4*>(&Xrow[k0 + 16 + lk]);
        const float4 wv0 = *reinterpret_cast<const float4*>(&Wrow[k0 + lk]);
        const float4 wv1 = *reinterpret_cast<const float4*>(&Wrow[k0 + 16 + lk]);
        __syncthreads();
        Xs[lk + 0][lrow] = xv0.x; Xs[lk + 1][lrow] = xv0.y;
        Xs[lk + 2][lrow] = xv0.z; Xs[lk + 3][lrow] = xv0.w;
        Xs[16 + lk + 0][lrow] = xv1.x; Xs[16 + lk + 1][lrow] = xv1.y;
        Xs[16 + lk + 2][lrow] = xv1.z; Xs[16 + lk + 3][lrow] = xv1.w;
        Ws[lk + 0][lrow] = wv0.x; Ws[lk + 1][lrow] = wv0.y;
        Ws[lk + 2][lrow] = wv0.z; Ws[lk + 3][lrow] = wv0.w;
        Ws[16 + lk + 0][lrow] = wv1.x; Ws[16 + lk + 1][lrow] = wv1.y;
        Ws[16 + lk + 2][lrow] = wv1.z; Ws[16 + lk + 3][lrow] = wv1.w;
        __syncthreads();

        #pragma unroll
        for (int kt = 0; kt < 2; kt++) {
            float fx[8], fw[8];
            #pragma unroll
            for (int j = 0; j < 8; j++) {
                fx[j] = Xs[16 * kt + 8 * h + j][32 * wm + c];
                fw[j] = Ws[16 * kt + 8 * h + j][32 * wn + c];
            }
            bfrag Ah, Al, Bh, Bl;
            cvt_hilo(fx, Ah, Al);
            cvt_hilo(fw, Bh, Bl);
            acc = __builtin_amdgcn_mfma_f32_32x32x16_bf16(Ah, Bh, acc, 0, 0, 0);
            acc = __builtin_amdgcn_mfma_f32_32x32x16_bf16(Ah, Bl, acc, 0, 0, 0);
            acc = __builtin_amdgcn_mfma_f32_32x32x16_bf16(Al, Bh, acc, 0, 0, 0);
        }
    }

    const float C2 = -0.0239861701969175f; // -2*ln(10000)/768
    const int n = n0 + 32 * wn + c;
    #pragma unroll
    for (int g = 0; g < 16; g++) {
        const int rr = (g & 3) + 8 * (g >> 2) + 4 * h;
        const int m  = m0 + 32 * wm + rr;
        if (m >= NM) continue;
        float v = acc[g] + bias[n];
        if (z < 2) {
            const int bpos = m / NS;  // pe indexed by BATCH position (faithful)
            const float ang = (float)bpos * expf((float)(n >> 1) * C2);
            v += (n & 1) ? cosf(ang) : sinf(ang);
        }
        out[(size_t)m * ND + n] = v;
    }
}

// ---------------- Kernel 2: attention via MFMA, one block per b ------------
// (R15 version, unchanged.)
__global__ __launch_bounds__(256, 1) void attn(
    const float* __restrict__ Q, const float* __restrict__ K,
    const float* __restrict__ V,
    const float* __restrict__ lin_w, const float* __restrict__ lin_b,
    float* __restrict__ Ag, float* __restrict__ ctx_out)
{
    const int b   = blockIdx.x;
    const int tid = threadIdx.x;
    const int w   = tid >> 6;          // wave 0..3
    const int l   = tid & 63;
    const int c   = l & 31;
    const int h   = l >> 5;

    __shared__ float Lsh[9 * 64 * 68];           // 153 KB
    float* SP = Lsh;                              // 4 partial S tiles
    float* QP = Lsh + 4 * 64 * 68;                // 4 partial Qt tiles
    float* Pf = Lsh + 8 * 64 * 68;                // P

    const float* __restrict__ Qb = Q + (size_t)b * NS * ND;
    const float* __restrict__ Kb = K + (size_t)b * NS * ND;
    const float* __restrict__ Vb = V + (size_t)b * NS * ND;

    f32x16 accS[2][2], accQ[2][2];
    #pragma unroll
    for (int mt = 0; mt < 2; mt++)
        #pragma unroll
        for (int nt = 0; nt < 2; nt++)
            #pragma unroll
            for (int g = 0; g < 16; g++) { accS[mt][nt][g] = 0.f; accQ[mt][nt][g] = 0.f; }

    const int ks = w * 192;
    for (int kt = 0; kt < 12; ++kt) {
        const int ko = ks + kt * 16 + 8 * h;
        bfrag Qh[2], Ql[2], Kh[2], Kl[2], Wh[2], Wl[2];
        #pragma unroll
        for (int mt = 0; mt < 2; mt++) {
            const int row = 32 * mt + c;
            const int r = (row < NS) ? row : 0;
            float f[8];
            {
                const float4 a0 = *reinterpret_cast<const float4*>(&Qb[(size_t)r * ND + ko]);
                const float4 a1 = *reinterpret_cast<const float4*>(&Qb[(size_t)r * ND + ko + 4]);
                f[0]=a0.x; f[1]=a0.y; f[2]=a0.z; f[3]=a0.w; f[4]=a1.x; f[5]=a1.y; f[6]=a1.z; f[7]=a1.w;
            }
            cvt_hilo(f, Qh[mt], Ql[mt]);
            {
                const float4 a0 = *reinterpret_cast<const float4*>(&Kb[(size_t)r * ND + ko]);
                const float4 a1 = *reinterpret_cast<const float4*>(&Kb[(size_t)r * ND + ko + 4]);
                f[0]=a0.x; f[1]=a0.y; f[2]=a0.z; f[3]=a0.w; f[4]=a1.x; f[5]=a1.y; f[6]=a1.z; f[7]=a1.w;
            }
            cvt_hilo(f, Kh[mt], Kl[mt]);
            {
                const float4 a0 = *reinterpret_cast<const float4*>(&lin_w[(size_t)r * ND + ko]);
                const float4 a1 = *reinterpret_cast<const float4*>(&lin_w[(size_t)r * ND + ko + 4]);
                f[0]=a0.x; f[1]=a0.y; f[2]=a0.z; f[3]=a0.w; f[4]=a1.x; f[5]=a1.y; f[6]=a1.z; f[7]=a1.w;
            }
            cvt_hilo(f, Wh[mt], Wl[mt]);
        }
        #pragma unroll
        for (int mt = 0; mt < 2; mt++)
            #pragma unroll
            for (int nt = 0; nt < 2; nt++) {
                f32x16 a = accS[mt][nt];
                a = __builtin_amdgcn_mfma_f32_32x32x16_bf16(Qh[mt], Kh[nt], a, 0, 0, 0);
                a = __builtin_amdgcn_mfma_f32_32x32x16_bf16(Qh[mt], Kl[nt], a, 0, 0, 0);
                a = __builtin_amdgcn_mfma_f32_32x32x16_bf16(Ql[mt], Kh[nt], a, 0, 0, 0);
                accS[mt][nt] = a;
                f32x16 q = accQ[mt][nt];
                q = __builtin_amdgcn_mfma_f32_32x32x16_bf16(Qh[mt], Wh[nt], q, 0, 0, 0);
                q = __builtin_amdgcn_mfma_f32_32x32x16_bf16(Qh[mt], Wl[nt], q, 0, 0, 0);
                q = __builtin_amdgcn_mfma_f32_32x32x16_bf16(Ql[mt], Wh[nt], q, 0, 0, 0);
                accQ[mt][nt] = q;
            }
    }

    {
        float* SPw = SP + w * (64 * 68);
        float* QPw = QP + w * (64 * 68);
        #pragma unroll
        for (int mt = 0; mt < 2; mt++)
            #pragma unroll
            for (int nt = 0; nt < 2; nt++)
                #pragma unroll
                for (int g = 0; g < 16; g++) {
                    const int rg  = 32 * mt + (g & 3) + 8 * (g >> 2) + 4 * h;
                    const int col = 32 * nt + c;
                    SPw[rg * 68 + col] = accS[mt][nt][g];
                    QPw[rg * 68 + col] = accQ[mt][nt][g];
                }
    }
    __syncthreads();

    {
        const int r  = tid >> 2;
        const int cg = (tid & 3) * 16;
        #pragma unroll
        for (int q4 = 0; q4 < 4; ++q4) {
            const int off = r * 68 + cg + q4 * 4;
            float4 s0 = *reinterpret_cast<const float4*>(&SP[off]);
            float4 s1 = *reinterpret_cast<const float4*>(&SP[64 * 68 + off]);
            float4 s2 = *reinterpret_cast<const float4*>(&SP[2 * 64 * 68 + off]);
            float4 s3 = *reinterpret_cast<const float4*>(&SP[3 * 64 * 68 + off]);
            float4 r4;
            r4.x = 8.f * ((s0.x + s1.x) + (s2.x + s3.x));
            r4.y = 8.f * ((s0.y + s1.y) + (s2.y + s3.y));
            r4.z = 8.f * ((s0.z + s1.z) + (s2.z + s3.z));
            r4.w = 8.f * ((s0.w + s1.w) + (s2.w + s3.w));
            *reinterpret_cast<float4*>(&SP[off]) = r4;
            float4 t0 = *reinterpret_cast<const float4*>(&QP[off]);
            float4 t1 = *reinterpret_cast<const float4*>(&QP[64 * 68 + off]);
            float4 t2 = *reinterpret_cast<const float4*>(&QP[2 * 64 * 68 + off]);
            float4 t3 = *reinterpret_cast<const float4*>(&QP[3 * 64 * 68 + off]);
            float4 u4;
            u4.x = (t0.x + t1.x) + (t2.x + t3.x);
            u4.y = (t0.y + t1.y) + (t2.y + t3.y);
            u4.z = (t0.z + t1.z) + (t2.z + t3.z);
            u4.w = (t0.w + t1.w) + (t2.w + t3.w);
            *reinterpret_cast<float4*>(&QP[off]) = u4;
        }
    }
    __syncthreads();

    if (tid < NS) {
        const float* Sr = SP + tid * 68;
        float mx = -INFINITY;
        for (int c2 = 0; c2 < NS; ++c2) mx = fmaxf(mx, Sr[c2]);
        float sum = 0.f;
        for (int c2 = 0; c2 < NS; ++c2) {
            const float e = expf(Sr[c2] - mx);
            Pf[tid * 68 + c2] = e;
            sum += e;
        }
        const float inv = 1.f / sum;
        for (int c2 = 0; c2 < NS; ++c2) Pf[tid * 68 + c2] *= inv;
        for (int c2 = NS; c2 < 64; ++c2) Pf[tid * 68 + c2] = 0.f;
    }
    for (int e = tid; e < NS * NS; e += 256) {
        const int r = e / NS, cc = e - r * NS;
        Ag[b * (NS * NS) + e] = GAMA * (QP[r * 68 + cc] + lin_b[cc]);
    }
    __syncthreads();

    bfrag Ph[2][4], Pl[2][4];
    #pragma unroll
    for (int mt = 0; mt < 2; mt++)
        #pragma unroll
        for (int kt = 0; kt < 4; kt++) {
            float f[8];
            #pragma unroll
            for (int j = 0; j < 8; j++)
                f[j] = Pf[(32 * mt + c) * 68 + kt * 16 + 8 * h + j];
            cvt_hilo(f, Ph[mt][kt], Pl[mt][kt]);
        }

    for (int j3 = 0; j3 < 3; ++j3) {
        const int dbase = (w * 3 + j3) * 64;
        f32x16 accC[2][2];
        #pragma unroll
        for (int mt = 0; mt < 2; mt++)
            #pragma unroll
            for (int nt = 0; nt < 2; nt++)
                #pragma unroll
                for (int g = 0; g < 16; g++) accC[mt][nt][g] = 0.f;

        #pragma unroll
        for (int nt = 0; nt < 2; nt++) {
            const int d = dbase + 32 * nt + c;
            #pragma unroll
            for (int kt = 0; kt < 4; kt++) {
                float f[8];
                #pragma unroll
                for (int j = 0; j < 8; j++) {
                    const int k2 = kt * 16 + 8 * h + j;
                    f[j] = (k2 < NS) ? Vb[(size_t)k2 * ND + d] : 0.f;
                }
                bfrag Bh, Bl;
                cvt_hilo(f, Bh, Bl);
                #pragma unroll
                for (int mt = 0; mt < 2; mt++) {
                    f32x16 a = accC[mt][nt];
                    a = __builtin_amdgcn_mfma_f32_32x32x16_bf16(Ph[mt][kt], Bh, a, 0, 0, 0);
                    a = __builtin_amdgcn_mfma_f32_32x32x16_bf16(Ph[mt][kt], Bl, a, 0, 0, 0);
                    a = __builtin_amdgcn_mfma_f32_32x32x16_bf16(Pl[mt][kt], Bh, a, 0, 0, 0);
                    accC[mt][nt] = a;
                }
            }
        }
        #pragma unroll
        for (int mt = 0; mt < 2; mt++)
            #pragma unroll
            for (int nt = 0; nt < 2; nt++)
                #pragma unroll
                for (int g = 0; g < 16; g++) {
                    const int rg = 32 * mt + (g & 3) + 8 * (g >> 2) + 4 * h;
                    if (rg < NS)
                        ctx_out[((size_t)b * NS + rg) * ND + dbase + 32 * nt + c] = accC[mt][nt][g];
                }
    }
}

// ---------------- Kernel 3: gamma-decay recurrence via MFMA ----------------
// R13 version EXACTLY (best measured, ~104us). Every structural alternative
// tested and slower: NT/plain stores identical (R10), contiguous coop-writes
// worse (R11), 2-step prefetch null (R12), 2-wave barrier split +17 (R17),
// 16-col 2x-TLP +9 (R19). Barrier-free single-wave program order + fat VMEM
// through an LDS layout-transpose is the local optimum for this recurrence.
__global__ __launch_bounds__(64, 1) void recur(
    const float* __restrict__ Ag, const float* __restrict__ ctx,
    float* __restrict__ rec)
{
    const int blk   = blockIdx.x;          // 0..1103
    const int b     = blk / 24;
    const int chunk = blk - b * 24;        // 0..23 -> 32 cols
    const int l     = threadIdx.x;
    const int c     = l & 31;
    const int h     = l >> 5;
    const int d0    = chunk * 32;
    const int srow  = l >> 3;              // 0..7
    const int scol  = (l & 7) * 4;         // 0,4..28

    __shared__ float Sf[64 * 32];
    __shared__ float Cx[64 * 32];

    const float* __restrict__ Ab = Ag + b * (NS * NS);
    bfrag Ah[2][4], Al[2][4];
    #pragma unroll
    for (int mt = 0; mt < 2; mt++) {
        const int row = 32 * mt + c;
        const bool rok = row < NS;
        const float* __restrict__ Arow = Ab + row * NS;
        #pragma unroll
        for (int kt = 0; kt < 4; kt++) {
            FragU uh, ul;
            #pragma unroll
            for (int t = 0; t < 4; t++) {
                const int k0 = 16 * kt + 8 * h + 2 * t;
                const float e = (rok && k0     < NS) ? Arow[k0]     : 0.f;
                const float o = (rok && k0 + 1 < NS) ? Arow[k0 + 1] : 0.f;
                const unsigned ue = __float_as_uint(e), uo = __float_as_uint(o);
                uh.u[t] = (ue >> 16) | (uo & 0xFFFF0000u);
                const float re = e - __uint_as_float(ue & 0xFFFF0000u);
                const float ro = o - __uint_as_float(uo & 0xFFFF0000u);
                ul.u[t] = (__float_as_uint(re) >> 16) | (__float_as_uint(ro) & 0xFFFF0000u);
            }
            Ah[mt][kt] = uh.f; Al[mt][kt] = ul.f;
        }
    }

    {
        const float4 z = make_float4(0.f, 0.f, 0.f, 0.f);
        *reinterpret_cast<float4*>(&Cx[(48 + srow) * 32 + scol]) = z;
        *reinterpret_cast<float4*>(&Cx[(56 + srow) * 32 + scol]) = z;
        *reinterpret_cast<float4*>(&Sf[(48 + srow) * 32 + scol]) = z;
        *reinterpret_cast<float4*>(&Sf[(56 + srow) * 32 + scol]) = z;
    }

    float4 creg[7];
    #pragma unroll
    for (int it = 0; it < 7; ++it) creg[it] = make_float4(0.f, 0.f, 0.f, 0.f);
    {
        const float* __restrict__ src = ctx + d0;
        #pragma unroll
        for (int it = 0; it < 7; ++it) {
            const int r = it * 8 + srow;
            if (r < NS)
                creg[it] = *reinterpret_cast<const float4*>(&src[(size_t)r * ND + scol]);
        }
        float* __restrict__ r0 = rec + (size_t)b * NS * ND + d0;
        #pragma unroll
        for (int it = 0; it < 7; ++it) {
            const int r = it * 8 + srow;
            if (r < NS) {
                *reinterpret_cast<float4*>(&Sf[r * 32 + scol]) = creg[it];
                *reinterpret_cast<float4*>(&r0[(size_t)r * ND + scol]) = creg[it];
            }
        }
    }
    {
        const float* __restrict__ src = ctx + (size_t)NS * ND + d0;
        #pragma unroll
        for (int it = 0; it < 7; ++it) {
            const int r = it * 8 + srow;
            if (r < NS)
                creg[it] = *reinterpret_cast<const float4*>(&src[(size_t)r * ND + scol]);
        }
    }

    for (int i = 1; i < NB; ++i) {
        #pragma unroll
        for (int it = 0; it < 7; ++it) {
            const int r = it * 8 + srow;
            if (r < NS)
                *reinterpret_cast<float4*>(&Cx[r * 32 + scol]) = creg[it];
        }
        if (i + 1 < NB) {
            const float* __restrict__ src = ctx + (size_t)(i + 1) * NS * ND + d0;
            #pragma unroll
            for (int it = 0; it < 7; ++it) {
                const int r = it * 8 + srow;
                if (r < NS)
                    creg[it] = *reinterpret_cast<const float4*>(&src[(size_t)r * ND + scol]);
            }
        }
        f32x16 acc[2];
        #pragma unroll
        for (int mt = 0; mt < 2; mt++)
            #pragma unroll
            for (int g = 0; g < 16; g++) {
                const int rg = 32 * mt + (g & 3) + 8 * (g >> 2) + 4 * h;
                acc[mt][g] = Cx[rg * 32 + c];
            }
        bfrag Bh[4], Bl[4];
        #pragma unroll
        for (int kt = 0; kt < 4; kt++) {
            float f[8];
            #pragma unroll
            for (int j = 0; j < 8; j++)
                f[j] = Sf[(16 * kt + 8 * h + j) * 32 + c];
            FragU uh, ul;
            #pragma unroll
            for (int t = 0; t < 4; t++) {
                const unsigned b0 = __float_as_uint(f[2 * t]);
                const unsigned b1 = __float_as_uint(f[2 * t + 1]);
                uh.u[t] = (b0 >> 16) | (b1 & 0xFFFF0000u);
                const float r0f = f[2 * t]     - __uint_as_float(b0 & 0xFFFF0000u);
                const float r1f = f[2 * t + 1] - __uint_as_float(b1 & 0xFFFF0000u);
                ul.u[t] = (__float_as_uint(r0f) >> 16) | (__float_as_uint(r1f) & 0xFFFF0000u);
            }
            Bh[kt] = uh.f; Bl[kt] = ul.f;
        }
        #pragma unroll
        for (int mt = 0; mt < 2; mt++) {
            f32x16 a = acc[mt];
            #pragma unroll
            for (int kt = 0; kt < 4; kt++)
                a = __builtin_amdgcn_mfma_f32_32x32x16_bf16(Ah[mt][kt], Bh[kt], a, 0, 0, 0);
            #pragma unroll
            for (int kt = 0; kt < 4; kt++)
                a = __builtin_amdgcn_mfma_f32_32x32x16_bf16(Ah[mt][kt], Bl[kt], a, 0, 0, 0);
            #pragma unroll
            for (int kt = 0; kt < 4; kt++)
                a = __builtin_amdgcn_mfma_f32_32x32x16_bf16(Al[mt][kt], Bh[kt], a, 0, 0, 0);
            acc[mt] = a;
        }
        #pragma unroll
        for (int mt = 0; mt < 2; mt++)
            #pragma unroll
            for (int g = 0; g < 16; g++) {
                const int rg = 32 * mt + (g & 3) + 8 * (g >> 2) + 4 * h;
                Sf[rg * 32 + c] = acc[mt][g];
            }
        float* __restrict__ reci = rec + (size_t)(i * NB + b) * NS * ND + d0;
        #pragma unroll
        for (int it = 0; it < 7; ++it) {
            const int r = it * 8 + srow;
            if (r < NS) {
                const float4 v = *reinterpret_cast<const float4*>(&Sf[r * 32 + scol]);
                *reinterpret_cast<float4*>(&reci[(size_t)r * ND + scol]) = v;
            }
        }
    }
}

extern "C" void kernel_launch(void* const* d_in, const int* in_sizes, int n_in,
                              void* d_out, int out_size, void* d_ws, size_t ws_size,
                              hipStream_t stream) {
    const float* text_emb = (const float*)d_in[0];
    const float* emb      = (const float*)d_in[1];
    const float* Wq = (const float*)d_in[2]; const float* bq = (const float*)d_in[3];
    const float* Wk = (const float*)d_in[4]; const float* bk = (const float*)d_in[5];
    const float* Wv = (const float*)d_in[6]; const float* bv = (const float*)d_in[7];
    const float* lw = (const float*)d_in[8]; const float* lb = (const float*)d_in[9];

    float* out = (float*)d_out;
    float* ctx = out;                          // [46,50,768]
    float* rec = out + NB * NS * ND;           // [46,46,50,768]

    float* ws = (float*)d_ws;                  // needs 21.7 MB
    float* Q  = ws;
    float* K  = Q + NB * NS * ND;
    float* V  = K + NB * NS * ND;
    float* Ag = V + NB * NS * ND;              // gamma * Q_trans, [46,50,50]

    qkv_gemm<<<dim3(36, 12, 3), 256, 0, stream>>>(text_emb, emb, Wq, bq, Wk, bk, Wv, bv, Q, K, V);
    attn<<<dim3(NB), 256, 0, stream>>>(Q, K, V, lw, lb, Ag, ctx);
    recur<<<dim3(1104), 64, 0, stream>>>(Ag, ctx, rec);
}